// Round 2
// baseline (266.743 us; speedup 1.0000x reference)
//
#include <hip/hip_runtime.h>

// IoU similarity: out[b,i,j] = background ? -1 : IoU(boxes1[b,i], boxes2[b,j])
// B=4, N=M=4096. Output 256 MiB fp32 -> memory(write)-bound, ~43us roofline.

typedef float f32x4 __attribute__((ext_vector_type(4)));

#define TPB  256   // threads per block
#define JPT  4     // boxes2 columns per thread (one float4 store)
#define ROWS 8     // boxes1 rows per block
#define COLS (TPB * JPT)  // 1024 columns per block

__global__ __launch_bounds__(TPB) void iou_kernel(
    const f32x4* __restrict__ b1,    // [B*N] boxes (x1,y1,x2,y2)
    const f32x4* __restrict__ b2,    // [B*M]
    float* __restrict__ out,         // [B*N*M]
    int N, int M)
{
    const int b  = blockIdx.z;
    const int i0 = blockIdx.y * ROWS;
    const int j0 = blockIdx.x * COLS + threadIdx.x * JPT;

    // ---- per-thread boxes2 columns: load once, hoist area/mask ----
    f32x4 q[JPT];
    float area2[JPT];
    bool  m2[JPT];
    const f32x4* b2p = b2 + (size_t)b * M + j0;
#pragma unroll
    for (int k = 0; k < JPT; ++k) {
        q[k] = b2p[k];
        area2[k] = (q[k].z - q[k].x) * (q[k].w - q[k].y);
        float mx = fmaxf(fmaxf(q[k].x, q[k].y), fmaxf(q[k].z, q[k].w));
        m2[k] = (mx < 0.0f);
    }

    const f32x4* b1p   = b1 + (size_t)b * N + i0;
    const size_t obase = ((size_t)b * N + (size_t)i0) * (size_t)M + (size_t)j0;

#pragma unroll
    for (int r = 0; r < ROWS; ++r) {
        // block-uniform address -> scalar load path
        f32x4 p = b1p[r];
        float area1 = (p.z - p.x) * (p.w - p.y);
        float mx1 = fmaxf(fmaxf(p.x, p.y), fmaxf(p.z, p.w));
        bool m1 = (mx1 < 0.0f);

        f32x4 o;
#pragma unroll
        for (int k = 0; k < JPT; ++k) {
            float ltx = fmaxf(p.x, q[k].x);
            float lty = fmaxf(p.y, q[k].y);
            float rbx = fminf(p.z, q[k].z);
            float rby = fminf(p.w, q[k].w);
            float w = fmaxf(rbx - ltx, 0.0f);
            float h = fmaxf(rby - lty, 0.0f);
            float inter = w * h;
            // match reference order: (area1 + area2) - inter
            float uni = (area1 + area2[k]) - inter;
            float iou = (uni > 0.0f) ? (inter / uni) : 0.0f;  // IEEE div, matches numpy
            o[k] = (m1 || m2[k]) ? -1.0f : iou;
        }
        __builtin_nontemporal_store(o, (f32x4*)(out + obase + (size_t)r * M));
    }
}

extern "C" void kernel_launch(void* const* d_in, const int* in_sizes, int n_in,
                              void* d_out, int out_size, void* d_ws, size_t ws_size,
                              hipStream_t stream) {
    const f32x4* b1 = (const f32x4*)d_in[0];
    const f32x4* b2 = (const f32x4*)d_in[1];
    float* out = (float*)d_out;

    const int N = 4096;
    const int M = 4096;
    const int B = in_sizes[0] / (4 * N);   // = 4

    dim3 grid(M / COLS, N / ROWS, B);      // (4, 512, 4)
    dim3 block(TPB);
    iou_kernel<<<grid, block, 0, stream>>>(b1, b2, out, N, M);
}

// Round 4
// 259.065 us; speedup vs baseline: 1.0296x; 1.0296x over previous
//
#include <hip/hip_runtime.h>

// IoU similarity: out[b,i,j] = background ? -1 : IoU(boxes1[b,i], boxes2[b,j])
// B=4, N=M=4096. Output 256 MiB fp32 -> write-bandwidth-bound, ~43us kernel floor.
// R2 lesson: nontemporal stores held kernel at ~2.7 TB/s (store-completion
// latency to HBM); regular stores retire into L2 and write back async.

typedef float f32x4 __attribute__((ext_vector_type(4)));

#define TPB  256   // threads per block
#define JPT  4     // boxes2 columns per thread (one float4 store)
#define ROWS 8     // boxes1 rows per block
#define COLS (TPB * JPT)  // 1024 columns per block

__global__ __launch_bounds__(TPB) void iou_kernel(
    const f32x4* __restrict__ b1,    // [B*N] boxes (x1,y1,x2,y2)
    const f32x4* __restrict__ b2,    // [B*M]
    float* __restrict__ out,         // [B*N*M]
    int N, int M)
{
    const int b  = blockIdx.z;
    const int i0 = blockIdx.y * ROWS;
    const int j0 = blockIdx.x * COLS + threadIdx.x * JPT;

    // ---- per-thread boxes2 columns: load once, hoist area/mask ----
    f32x4 q[JPT];
    float area2[JPT];
    bool  m2[JPT];
    const f32x4* b2p = b2 + (size_t)b * M + j0;
#pragma unroll
    for (int k = 0; k < JPT; ++k) {
        q[k] = b2p[k];
        area2[k] = (q[k].z - q[k].x) * (q[k].w - q[k].y);
        float mx = fmaxf(fmaxf(q[k].x, q[k].y), fmaxf(q[k].z, q[k].w));
        m2[k] = (mx < 0.0f);
    }

    const f32x4* b1p   = b1 + (size_t)b * N + i0;
    const size_t obase = ((size_t)b * N + (size_t)i0) * (size_t)M + (size_t)j0;

#pragma unroll
    for (int r = 0; r < ROWS; ++r) {
        // block-uniform address -> scalar load path
        f32x4 p = b1p[r];
        float area1 = (p.z - p.x) * (p.w - p.y);
        float mx1 = fmaxf(fmaxf(p.x, p.y), fmaxf(p.z, p.w));
        bool m1 = (mx1 < 0.0f);

        f32x4 o;
#pragma unroll
        for (int k = 0; k < JPT; ++k) {
            float ltx = fmaxf(p.x, q[k].x);
            float lty = fmaxf(p.y, q[k].y);
            float rbx = fminf(p.z, q[k].z);
            float rby = fminf(p.w, q[k].w);
            float w = fmaxf(rbx - ltx, 0.0f);
            float h = fmaxf(rby - lty, 0.0f);
            float inter = w * h;
            // match reference order: (area1 + area2) - inter
            float uni = (area1 + area2[k]) - inter;
            // fast reciprocal (v_rcp_f32, ~1e-7 rel err << 2e-2 threshold)
            float iou = (uni > 0.0f) ? (inter * __builtin_amdgcn_rcpf(uni)) : 0.0f;
            o[k] = (m1 || m2[k]) ? -1.0f : iou;
        }
        *(f32x4*)(out + obase + (size_t)r * M) = o;   // regular store, via L2
    }
}

extern "C" void kernel_launch(void* const* d_in, const int* in_sizes, int n_in,
                              void* d_out, int out_size, void* d_ws, size_t ws_size,
                              hipStream_t stream) {
    const f32x4* b1 = (const f32x4*)d_in[0];
    const f32x4* b2 = (const f32x4*)d_in[1];
    float* out = (float*)d_out;

    const int N = 4096;
    const int M = 4096;
    const int B = in_sizes[0] / (4 * N);   // = 4

    dim3 grid(M / COLS, N / ROWS, B);      // (4, 512, 4)
    dim3 block(TPB);
    iou_kernel<<<grid, block, 0, stream>>>(b1, b2, out, N, M);
}